// Round 1
// baseline (602.040 us; speedup 1.0000x reference)
//
#include <hip/hip_runtime.h>
#include <hip/hip_bf16.h>
#include <string.h>

#define S3 110592  // 48^3
#define CDIM 96
#define EDIM 384

typedef __attribute__((ext_vector_type(8))) short bf16x8;
typedef __attribute__((ext_vector_type(4))) float f32x4;
typedef unsigned short ushort_t;

__device__ __forceinline__ ushort_t f2bf(float f) {
  __hip_bfloat16 h = __float2bfloat16(f);
  union { __hip_bfloat16 h; ushort_t u; } cv; cv.h = h; return cv.u;
}
__device__ __forceinline__ float bf2f(ushort_t u) {
  union { __hip_bfloat16 h; ushort_t u; } cv; cv.u = u; return __bfloat162float(cv.h);
}

// ---------------------------------------------------------------- prep: pack w1 (fold ln_w), b1f (fold ln_b), bias2 (fold grn_b via w2)
__global__ void kprep(const float* __restrict__ ln_w, const float* __restrict__ ln_b,
                      const float* __restrict__ w1, const float* __restrict__ b1,
                      const float* __restrict__ grn_b, const float* __restrict__ w2,
                      const float* __restrict__ b2,
                      ushort_t* __restrict__ w1p, float* __restrict__ b1f, float* __restrict__ bias2) {
  int idx = blockIdx.x * 256 + threadIdx.x;
  if (idx < 24 * 3 * 64 * 8) {
    int j = idx & 7, lane = (idx >> 3) & 63, ks = (idx >> 9) % 3, nt = idx / 1536;
    int c = ks * 32 + (lane >> 4) * 8 + j;
    int e = nt * 16 + (lane & 15);
    w1p[idx] = f2bf(ln_w[c] * w1[c * EDIM + e]);
  }
  if (idx < EDIM) {
    float s = b1[idx];
    for (int c = 0; c < CDIM; ++c) s += ln_b[c] * w1[c * EDIM + idx];
    b1f[idx] = s;
  }
  if (idx < CDIM) {
    float s = b2[idx];
    for (int e = 0; e < EDIM; ++e) s += grn_b[e] * w2[e * CDIM + idx];
    bias2[idx] = s;
  }
}

// ---------------------------------------------------------------- depthwise 7x7x7 conv, channels-first, bf16 out
// block 256: tile z=8 (2 thread-layers x Rz=4), y=16, x=48 (8 threads x Rx=6)
__global__ __launch_bounds__(256, 2) void kconv(const float* __restrict__ x,
                                                const float* __restrict__ dw_w,
                                                const float* __restrict__ dw_b,
                                                ushort_t* __restrict__ y) {
  __shared__ float xt[14 * 22 * 56];
  __shared__ float wl[343];
  __shared__ float bias_s;
  int bid = blockIdx.x;
  int yt = bid % 3, zt = (bid / 3) % 6, bc = bid / 18;
  int c = bc % 96;
  int z0 = zt * 8, y0 = yt * 16;
  size_t base = (size_t)bc * S3;
  int tid = threadIdx.x;

  for (int i = tid; i < 343; i += 256) wl[i] = dw_w[c * 343 + i];
  if (tid == 0) bias_s = dw_b[c];
  for (int i = tid; i < 14 * 22 * 54; i += 256) {
    int dx = i % 54; int t2 = i / 54; int dy = t2 % 22; int dz = t2 / 22;
    int gz = z0 - 3 + dz, gy = y0 - 3 + dy, gx = dx - 3;
    float v = 0.f;
    if ((unsigned)gz < 48u && (unsigned)gy < 48u && (unsigned)gx < 48u)
      v = x[base + (size_t)gz * 2304 + gy * 48 + gx];
    xt[(dz * 22 + dy) * 56 + dx] = v;
  }
  __syncthreads();

  int xr_t = tid & 7, yy = (tid >> 3) & 15, zz = tid >> 7;
  int x0 = xr_t * 6;
  float acc[4][6];
#pragma unroll
  for (int a = 0; a < 4; ++a)
#pragma unroll
    for (int bI = 0; bI < 6; ++bI) acc[a][bI] = 0.f;

  for (int ty = 0; ty < 7; ++ty) {
    float wv[49];
#pragma unroll
    for (int i = 0; i < 49; ++i) wv[i] = wl[(i / 7) * 49 + ty * 7 + (i % 7)];
    int ly = yy + ty;
#pragma unroll
    for (int zrow = 0; zrow < 10; ++zrow) {
      int lz = zz * 4 + zrow;
      const float* rowp = &xt[(lz * 22 + ly) * 56 + x0];
      float vals[12];
#pragma unroll
      for (int j = 0; j < 12; ++j) vals[j] = rowp[j];
#pragma unroll
      for (int tz = 0; tz < 7; ++tz) {
        int zr = zrow - tz;
        if (zr >= 0 && zr < 4) {
#pragma unroll
          for (int tx = 0; tx < 7; ++tx) {
            float w = wv[tz * 7 + tx];
#pragma unroll
            for (int xr = 0; xr < 6; ++xr)
              acc[zr][xr] = fmaf(vals[tx + xr], w, acc[zr][xr]);
          }
        }
      }
    }
  }

  float bv = bias_s;
#pragma unroll
  for (int zr = 0; zr < 4; ++zr) {
    int z = z0 + zz * 4 + zr;
    size_t o = base + (size_t)z * 2304 + (size_t)(y0 + yy) * 48 + x0;
#pragma unroll
    for (int xp = 0; xp < 3; ++xp) {
      unsigned pk = ((unsigned)f2bf(acc[zr][2 * xp] + bv)) |
                    ((unsigned)f2bf(acc[zr][2 * xp + 1] + bv) << 16);
      *(unsigned*)&y[o + 2 * xp] = pk;
    }
  }
}

// ---------------------------------------------------------------- LN + GEMM1(96->384) + GELU + sumsq
// block 256 (4 waves), 64 positions per block; wave q owns e-range [q*96, q*96+96)
__global__ __launch_bounds__(256, 2) void kmlp1(const ushort_t* __restrict__ y,
                                                const ushort_t* __restrict__ w1p,
                                                const float* __restrict__ b1f,
                                                ushort_t* __restrict__ h,
                                                float* __restrict__ sumsq) {
  __shared__ ushort_t Al[64 * 104];
  __shared__ float red_s[4][64], red_q[4][64];
  __shared__ float stat_mu[64], stat_rv[64];
  int tid = threadIdx.x;
  int q = tid >> 6, lane = tid & 63;
  size_t pos0 = (size_t)blockIdx.x * 64;
  int b = (int)(pos0 / S3);
  int sp0 = (int)(pos0 % S3);

  float v[24];
  float s = 0.f, ss = 0.f;
  const ushort_t* yb = y + (size_t)b * 96 * S3 + sp0 + lane;
#pragma unroll
  for (int i = 0; i < 24; ++i) {
    int cc = q * 24 + i;
    float f = bf2f(yb[(size_t)cc * S3]);
    v[i] = f; s += f; ss += f * f;
  }
  red_s[q][lane] = s; red_q[q][lane] = ss;
  __syncthreads();
  if (tid < 64) {
    float su = red_s[0][tid] + red_s[1][tid] + red_s[2][tid] + red_s[3][tid];
    float sq = red_q[0][tid] + red_q[1][tid] + red_q[2][tid] + red_q[3][tid];
    float mu = su * (1.f / 96.f);
    float var = sq * (1.f / 96.f) - mu * mu;
    stat_mu[tid] = mu;
    stat_rv[tid] = rsqrtf(var + 1e-6f);
  }
  __syncthreads();
  {
    float mu = stat_mu[lane], rv = stat_rv[lane];
#pragma unroll
    for (int i4 = 0; i4 < 6; ++i4) {
      ushort_t u0 = f2bf((v[i4 * 4 + 0] - mu) * rv);
      ushort_t u1 = f2bf((v[i4 * 4 + 1] - mu) * rv);
      ushort_t u2 = f2bf((v[i4 * 4 + 2] - mu) * rv);
      ushort_t u3 = f2bf((v[i4 * 4 + 3] - mu) * rv);
      uint2 t; t.x = (unsigned)u0 | ((unsigned)u1 << 16); t.y = (unsigned)u2 | ((unsigned)u3 << 16);
      *(uint2*)&Al[lane * 104 + q * 24 + i4 * 4] = t;
    }
  }
  __syncthreads();

  f32x4 acc[4][6];
#pragma unroll
  for (int mt = 0; mt < 4; ++mt)
#pragma unroll
    for (int ntl = 0; ntl < 6; ++ntl) acc[mt][ntl] = (f32x4){0.f, 0.f, 0.f, 0.f};

  int row = lane & 15, g = lane >> 4;
#pragma unroll
  for (int ks = 0; ks < 3; ++ks) {
    bf16x8 af[4];
    int colb = ks * 32 + g * 8;
#pragma unroll
    for (int mt = 0; mt < 4; ++mt)
      af[mt] = *(const bf16x8*)&Al[(mt * 16 + row) * 104 + colb];
#pragma unroll
    for (int ntl = 0; ntl < 6; ++ntl) {
      bf16x8 bfg = *(const bf16x8*)&w1p[(size_t)(((q * 6 + ntl) * 3 + ks) * 64 + lane) * 8];
#pragma unroll
      for (int mt = 0; mt < 4; ++mt)
        acc[mt][ntl] = __builtin_amdgcn_mfma_f32_16x16x32_bf16(af[mt], bfg, acc[mt][ntl], 0, 0, 0);
    }
  }

#pragma unroll
  for (int ntl = 0; ntl < 6; ++ntl) {
    int e = q * 96 + ntl * 16 + row;
    float bb = b1f[e];
    float ssq = 0.f;
#pragma unroll
    for (int mt = 0; mt < 4; ++mt) {
#pragma unroll
      for (int r = 0; r < 4; ++r) {
        float val = acc[mt][ntl][r] + bb;
        float gel = 0.5f * val * (1.f + erff(val * 0.70710678118f));
        size_t p = pos0 + mt * 16 + g * 4 + r;
        h[p * EDIM + e] = f2bf(gel);
        ssq += gel * gel;
      }
    }
    ssq += __shfl_xor(ssq, 16, 64);
    ssq += __shfl_xor(ssq, 32, 64);
    if (g == 0) atomicAdd(&sumsq[b * EDIM + e], ssq);
  }
}

// ---------------------------------------------------------------- GRN scale per (b,e)
__global__ void kscale(const float* __restrict__ sumsq, const float* __restrict__ grn_w,
                       float* __restrict__ scale) {
  __shared__ float wsum[6];
  __shared__ float mean_s;
  int b = blockIdx.x, e = threadIdx.x;  // 384 threads
  float gv = sqrtf(sumsq[b * EDIM + e]);
  float t = gv;
#pragma unroll
  for (int off = 1; off <= 32; off <<= 1) t += __shfl_xor(t, off, 64);
  if ((e & 63) == 0) wsum[e >> 6] = t;
  __syncthreads();
  if (e == 0) {
    float m = 0.f;
    for (int i = 0; i < 6; ++i) m += wsum[i];
    mean_s = m * (1.f / EDIM);
  }
  __syncthreads();
  scale[b * EDIM + e] = grn_w[e] * (gv / (mean_s + 1e-6f)) + 1.f;
}

// ---------------------------------------------------------------- pack scale-folded w2 per batch (MFMA fragment order)
__global__ void kpackw2(const float* __restrict__ scale, const float* __restrict__ w2,
                        ushort_t* __restrict__ w2s) {
  int idx = blockIdx.x * 256 + threadIdx.x;  // exactly 2*36864
  int b = idx / 36864; int r = idx % 36864;
  int j = r & 7, lane = (r >> 3) & 63, ks = (r >> 9) % 12, nt = r / 6144;
  int e = ks * 32 + (lane >> 4) * 8 + j, cc = nt * 16 + (lane & 15);
  w2s[idx] = f2bf(scale[b * EDIM + e] * w2[e * CDIM + cc]);
}

// ---------------------------------------------------------------- GEMM2(384->96) + bias2 + residual, channels-first out
// block 256 (4 waves), 64 positions; wave w owns m-tile w; all 6 n-tiles
__global__ __launch_bounds__(256, 2) void kmlp2(const ushort_t* __restrict__ h,
                                                const ushort_t* __restrict__ w2s,
                                                const float* __restrict__ bias2,
                                                const float* __restrict__ x,
                                                float* __restrict__ out) {
  __shared__ float tile[96 * 65];
  int tid = threadIdx.x;
  int w = tid >> 6, lane = tid & 63;
  size_t pos0 = (size_t)blockIdx.x * 64;
  int b = (int)(pos0 / S3);
  int sp0 = (int)(pos0 % S3);
  int row = lane & 15, g = lane >> 4;

  f32x4 acc[6];
#pragma unroll
  for (int nt = 0; nt < 6; ++nt) acc[nt] = (f32x4){0.f, 0.f, 0.f, 0.f};

  const ushort_t* w2b = w2s + (size_t)b * 36864;
  size_t abase = (pos0 + w * 16 + row) * (size_t)EDIM + g * 8;
#pragma unroll
  for (int ks = 0; ks < 12; ++ks) {
    bf16x8 af = *(const bf16x8*)&h[abase + ks * 32];
#pragma unroll
    for (int nt = 0; nt < 6; ++nt) {
      bf16x8 bfg = *(const bf16x8*)&w2b[(size_t)((nt * 12 + ks) * 64 + lane) * 8];
      acc[nt] = __builtin_amdgcn_mfma_f32_16x16x32_bf16(af, bfg, acc[nt], 0, 0, 0);
    }
  }

#pragma unroll
  for (int nt = 0; nt < 6; ++nt) {
    int cc = nt * 16 + row;
#pragma unroll
    for (int r = 0; r < 4; ++r)
      tile[cc * 65 + w * 16 + g * 4 + r] = acc[nt][r];
  }
  __syncthreads();
#pragma unroll
  for (int k = 0; k < 24; ++k) {
    int idx = tid + k * 256;
    int cc = idx >> 6, p = idx & 63;
    size_t o = (size_t)(b * 96 + cc) * S3 + sp0 + p;
    out[o] = x[o] + tile[cc * 65 + p] + bias2[cc];
  }
}

// ----------------------------------------------------------------
extern "C" void kernel_launch(void* const* d_in, const int* in_sizes, int n_in,
                              void* d_out, int out_size, void* d_ws, size_t ws_size,
                              hipStream_t stream) {
  const float* x     = (const float*)d_in[0];
  const float* dw_w  = (const float*)d_in[1];
  const float* dw_b  = (const float*)d_in[2];
  const float* ln_w  = (const float*)d_in[3];
  const float* ln_b  = (const float*)d_in[4];
  const float* w1    = (const float*)d_in[5];
  const float* b1    = (const float*)d_in[6];
  const float* grn_w = (const float*)d_in[7];
  const float* grn_b = (const float*)d_in[8];
  const float* w2    = (const float*)d_in[9];
  const float* b2    = (const float*)d_in[10];
  float* out = (float*)d_out;

  char* ws = (char*)d_ws;
  size_t off = 0;
  auto alloc = [&](size_t bytes) -> void* {
    void* p = ws + off;
    off = (off + bytes + 511) & ~(size_t)511;
    return p;
  };
  ushort_t* y   = (ushort_t*)alloc((size_t)2 * 96 * S3 * 2);        // 42.5 MB bf16 conv out
  ushort_t* h   = (ushort_t*)alloc((size_t)221184 * EDIM * 2);      // 170 MB bf16 hidden
  ushort_t* w1p = (ushort_t*)alloc(36864 * 2);
  ushort_t* w2s = (ushort_t*)alloc((size_t)2 * 36864 * 2);
  float* b1f    = (float*)alloc(EDIM * 4);
  float* bias2  = (float*)alloc(CDIM * 4);
  float* sumsq  = (float*)alloc(2 * EDIM * 4);
  float* scale  = (float*)alloc(2 * EDIM * 4);

  hipMemsetAsync(sumsq, 0, 2 * EDIM * 4, stream);
  kprep<<<145, 256, 0, stream>>>(ln_w, ln_b, w1, b1, grn_b, w2, b2, w1p, b1f, bias2);
  kconv<<<3456, 256, 0, stream>>>(x, dw_w, dw_b, y);
  kmlp1<<<3456, 256, 0, stream>>>(y, w1p, b1f, h, sumsq);
  kscale<<<2, 384, 0, stream>>>(sumsq, grn_w, scale);
  kpackw2<<<288, 256, 0, stream>>>(scale, w2, w2s);
  kmlp2<<<3456, 256, 0, stream>>>(h, w2s, bias2, x, out);
}

// Round 2
// 579.052 us; speedup vs baseline: 1.0397x; 1.0397x over previous
//
#include <hip/hip_runtime.h>
#include <hip/hip_bf16.h>
#include <string.h>

#define S3 110592  // 48^3
#define CDIM 96
#define EDIM 384

typedef __attribute__((ext_vector_type(8))) short bf16x8;
typedef __attribute__((ext_vector_type(4))) float f32x4;
typedef unsigned short ushort_t;

__device__ __forceinline__ ushort_t f2bf(float f) {
  __hip_bfloat16 h = __float2bfloat16(f);
  union { __hip_bfloat16 h; ushort_t u; } cv; cv.h = h; return cv.u;
}
__device__ __forceinline__ float bf2f(ushort_t u) {
  union { __hip_bfloat16 h; ushort_t u; } cv; cv.u = u; return __bfloat162float(cv.h);
}

// ---------------------------------------------------------------- prep: pack w1 (fold ln_w), b1f (fold ln_b), bias2 (fold grn_b via w2)
__global__ void kprep(const float* __restrict__ ln_w, const float* __restrict__ ln_b,
                      const float* __restrict__ w1, const float* __restrict__ b1,
                      const float* __restrict__ grn_b, const float* __restrict__ w2,
                      const float* __restrict__ b2,
                      ushort_t* __restrict__ w1p, float* __restrict__ b1f, float* __restrict__ bias2) {
  int idx = blockIdx.x * 256 + threadIdx.x;
  if (idx < 24 * 3 * 64 * 8) {
    int j = idx & 7, lane = (idx >> 3) & 63, ks = (idx >> 9) % 3, nt = idx / 1536;
    int c = ks * 32 + (lane >> 4) * 8 + j;
    int e = nt * 16 + (lane & 15);
    w1p[idx] = f2bf(ln_w[c] * w1[c * EDIM + e]);
  }
  if (idx < EDIM) {
    float s = b1[idx];
    for (int c = 0; c < CDIM; ++c) s += ln_b[c] * w1[c * EDIM + idx];
    b1f[idx] = s;
  }
  if (idx < CDIM) {
    float s = b2[idx];
    for (int e = 0; e < EDIM; ++e) s += grn_b[e] * w2[e * CDIM + idx];
    bias2[idx] = s;
  }
}

// ---------------------------------------------------------------- depthwise 7x7x7 conv, channels-first, bf16 out
// block 256 threads: 8 x-threads (Rx=6), 8 y, 4 z-threads (Rz=2). Tile z=8,y=8,x=48.
// LDS: 14 planes x 14 rows x 54 cols fp32 (stride 54, 8B-aligned rows) = 41.3 KB -> 3 blocks/CU.
// Weights read via block-uniform global loads -> SGPRs (scalar pipe), FMA uses SGPR operand.
__global__ __launch_bounds__(256, 3) void kconv(const float* __restrict__ x,
                                                const float* __restrict__ dw_w,
                                                const float* __restrict__ dw_b,
                                                ushort_t* __restrict__ y) {
  __shared__ float tile[14 * 14 * 54];
  int bid = blockIdx.x;
  int yt = bid % 6, zt = (bid / 6) % 6, bc = bid / 36;
  int c = bc % 96;
  int z0 = zt * 8, y0 = yt * 8;
  size_t base = (size_t)bc * S3;
  int tid = threadIdx.x;

  // stage 14x14x54 input tile (zero-padded halo)
  for (int i = tid; i < 14 * 14 * 54; i += 256) {
    int dx = i % 54; int t = i / 54; int dy = t % 14; int dz = t / 14;
    int gz = z0 - 3 + dz, gy = y0 - 3 + dy, gx = dx - 3;
    float v = 0.f;
    if ((unsigned)gz < 48u && (unsigned)gy < 48u && (unsigned)gx < 48u)
      v = x[base + (size_t)gz * 2304 + gy * 48 + gx];
    tile[(dz * 14 + dy) * 54 + dx] = v;
  }
  __syncthreads();

  int xt = tid & 7, yy = (tid >> 3) & 7, zz = tid >> 6;  // zz in 0..3
  int x0 = xt * 6;
  const float* __restrict__ wc = dw_w + c * 343;  // block-uniform -> s_load

  float acc[2][6];
#pragma unroll
  for (int a = 0; a < 2; ++a)
#pragma unroll
    for (int bI = 0; bI < 6; ++bI) acc[a][bI] = 0.f;

  for (int ty = 0; ty < 7; ++ty) {
    // 49 weights for this ky, uniform -> SGPRs
    float wr[49];
#pragma unroll
    for (int i = 0; i < 49; ++i) wr[i] = wc[(i / 7) * 49 + ty * 7 + (i % 7)];  // wr[tz*7+tx]
    int ly = yy + ty;
#pragma unroll
    for (int lp = 0; lp < 8; ++lp) {  // input planes zz*2 + lp
      const float* rp = &tile[(((zz << 1) + lp) * 14 + ly) * 54 + x0];
      float v[12];
#pragma unroll
      for (int j = 0; j < 6; ++j) {
        float2 t2 = *(const float2*)&rp[2 * j];
        v[2 * j] = t2.x; v[2 * j + 1] = t2.y;
      }
#pragma unroll
      for (int zr = 0; zr < 2; ++zr) {
        int tz = lp - zr;
        if (tz >= 0 && tz < 7) {
#pragma unroll
          for (int tx = 0; tx < 7; ++tx) {
            float w = wr[tz * 7 + tx];
#pragma unroll
            for (int xr = 0; xr < 6; ++xr)
              acc[zr][xr] = fmaf(v[tx + xr], w, acc[zr][xr]);
          }
        }
      }
    }
  }

  float bv = dw_b[c];
#pragma unroll
  for (int zr = 0; zr < 2; ++zr) {
    int z = z0 + (zz << 1) + zr;
    size_t o = base + (size_t)z * 2304 + (size_t)(y0 + yy) * 48 + x0;
#pragma unroll
    for (int xp = 0; xp < 3; ++xp) {
      unsigned pk = ((unsigned)f2bf(acc[zr][2 * xp] + bv)) |
                    ((unsigned)f2bf(acc[zr][2 * xp + 1] + bv) << 16);
      *(unsigned*)&y[o + 2 * xp] = pk;
    }
  }
}

// ---------------------------------------------------------------- LN + GEMM1(96->384) + GELU + sumsq
// block 256 (4 waves), 64 positions per block; wave q owns e-range [q*96, q*96+96)
__global__ __launch_bounds__(256, 2) void kmlp1(const ushort_t* __restrict__ y,
                                                const ushort_t* __restrict__ w1p,
                                                const float* __restrict__ b1f,
                                                ushort_t* __restrict__ h,
                                                float* __restrict__ sumsq) {
  __shared__ ushort_t Al[64 * 104];
  __shared__ float red_s[4][64], red_q[4][64];
  __shared__ float stat_mu[64], stat_rv[64];
  int tid = threadIdx.x;
  int q = tid >> 6, lane = tid & 63;
  size_t pos0 = (size_t)blockIdx.x * 64;
  int b = (int)(pos0 / S3);
  int sp0 = (int)(pos0 % S3);

  float v[24];
  float s = 0.f, ss = 0.f;
  const ushort_t* yb = y + (size_t)b * 96 * S3 + sp0 + lane;
#pragma unroll
  for (int i = 0; i < 24; ++i) {
    int cc = q * 24 + i;
    float f = bf2f(yb[(size_t)cc * S3]);
    v[i] = f; s += f; ss += f * f;
  }
  red_s[q][lane] = s; red_q[q][lane] = ss;
  __syncthreads();
  if (tid < 64) {
    float su = red_s[0][tid] + red_s[1][tid] + red_s[2][tid] + red_s[3][tid];
    float sq = red_q[0][tid] + red_q[1][tid] + red_q[2][tid] + red_q[3][tid];
    float mu = su * (1.f / 96.f);
    float var = sq * (1.f / 96.f) - mu * mu;
    stat_mu[tid] = mu;
    stat_rv[tid] = rsqrtf(var + 1e-6f);
  }
  __syncthreads();
  {
    float mu = stat_mu[lane], rv = stat_rv[lane];
#pragma unroll
    for (int i4 = 0; i4 < 6; ++i4) {
      ushort_t u0 = f2bf((v[i4 * 4 + 0] - mu) * rv);
      ushort_t u1 = f2bf((v[i4 * 4 + 1] - mu) * rv);
      ushort_t u2 = f2bf((v[i4 * 4 + 2] - mu) * rv);
      ushort_t u3 = f2bf((v[i4 * 4 + 3] - mu) * rv);
      uint2 t; t.x = (unsigned)u0 | ((unsigned)u1 << 16); t.y = (unsigned)u2 | ((unsigned)u3 << 16);
      *(uint2*)&Al[lane * 104 + q * 24 + i4 * 4] = t;
    }
  }
  __syncthreads();

  f32x4 acc[4][6];
#pragma unroll
  for (int mt = 0; mt < 4; ++mt)
#pragma unroll
    for (int ntl = 0; ntl < 6; ++ntl) acc[mt][ntl] = (f32x4){0.f, 0.f, 0.f, 0.f};

  int row = lane & 15, g = lane >> 4;
#pragma unroll
  for (int ks = 0; ks < 3; ++ks) {
    bf16x8 af[4];
    int colb = ks * 32 + g * 8;
#pragma unroll
    for (int mt = 0; mt < 4; ++mt)
      af[mt] = *(const bf16x8*)&Al[(mt * 16 + row) * 104 + colb];
#pragma unroll
    for (int ntl = 0; ntl < 6; ++ntl) {
      bf16x8 bfg = *(const bf16x8*)&w1p[(size_t)(((q * 6 + ntl) * 3 + ks) * 64 + lane) * 8];
#pragma unroll
      for (int mt = 0; mt < 4; ++mt)
        acc[mt][ntl] = __builtin_amdgcn_mfma_f32_16x16x32_bf16(af[mt], bfg, acc[mt][ntl], 0, 0, 0);
    }
  }

#pragma unroll
  for (int ntl = 0; ntl < 6; ++ntl) {
    int e = q * 96 + ntl * 16 + row;
    float bb = b1f[e];
    float ssq = 0.f;
#pragma unroll
    for (int mt = 0; mt < 4; ++mt) {
#pragma unroll
      for (int r = 0; r < 4; ++r) {
        float val = acc[mt][ntl][r] + bb;
        float gel = 0.5f * val * (1.f + erff(val * 0.70710678118f));
        size_t p = pos0 + mt * 16 + g * 4 + r;
        h[p * EDIM + e] = f2bf(gel);
        ssq += gel * gel;
      }
    }
    ssq += __shfl_xor(ssq, 16, 64);
    ssq += __shfl_xor(ssq, 32, 64);
    if (g == 0) atomicAdd(&sumsq[b * EDIM + e], ssq);
  }
}

// ---------------------------------------------------------------- GRN scale per (b,e)
__global__ void kscale(const float* __restrict__ sumsq, const float* __restrict__ grn_w,
                       float* __restrict__ scale) {
  __shared__ float wsum[6];
  __shared__ float mean_s;
  int b = blockIdx.x, e = threadIdx.x;  // 384 threads
  float gv = sqrtf(sumsq[b * EDIM + e]);
  float t = gv;
#pragma unroll
  for (int off = 1; off <= 32; off <<= 1) t += __shfl_xor(t, off, 64);
  if ((e & 63) == 0) wsum[e >> 6] = t;
  __syncthreads();
  if (e == 0) {
    float m = 0.f;
    for (int i = 0; i < 6; ++i) m += wsum[i];
    mean_s = m * (1.f / EDIM);
  }
  __syncthreads();
  scale[b * EDIM + e] = grn_w[e] * (gv / (mean_s + 1e-6f)) + 1.f;
}

// ---------------------------------------------------------------- pack scale-folded w2 per batch (MFMA fragment order)
__global__ void kpackw2(const float* __restrict__ scale, const float* __restrict__ w2,
                        ushort_t* __restrict__ w2s) {
  int idx = blockIdx.x * 256 + threadIdx.x;  // exactly 2*36864
  int b = idx / 36864; int r = idx % 36864;
  int j = r & 7, lane = (r >> 3) & 63, ks = (r >> 9) % 12, nt = r / 6144;
  int e = ks * 32 + (lane >> 4) * 8 + j, cc = nt * 16 + (lane & 15);
  w2s[idx] = f2bf(scale[b * EDIM + e] * w2[e * CDIM + cc]);
}

// ---------------------------------------------------------------- GEMM2(384->96) + bias2 + residual, channels-first out
// block 256 (4 waves), 64 positions; wave w owns m-tile w; all 6 n-tiles
__global__ __launch_bounds__(256, 2) void kmlp2(const ushort_t* __restrict__ h,
                                                const ushort_t* __restrict__ w2s,
                                                const float* __restrict__ bias2,
                                                const float* __restrict__ x,
                                                float* __restrict__ out) {
  __shared__ float tile[96 * 65];
  int tid = threadIdx.x;
  int w = tid >> 6, lane = tid & 63;
  size_t pos0 = (size_t)blockIdx.x * 64;
  int b = (int)(pos0 / S3);
  int sp0 = (int)(pos0 % S3);
  int row = lane & 15, g = lane >> 4;

  f32x4 acc[6];
#pragma unroll
  for (int nt = 0; nt < 6; ++nt) acc[nt] = (f32x4){0.f, 0.f, 0.f, 0.f};

  const ushort_t* w2b = w2s + (size_t)b * 36864;
  size_t abase = (pos0 + w * 16 + row) * (size_t)EDIM + g * 8;
#pragma unroll
  for (int ks = 0; ks < 12; ++ks) {
    bf16x8 af = *(const bf16x8*)&h[abase + ks * 32];
#pragma unroll
    for (int nt = 0; nt < 6; ++nt) {
      bf16x8 bfg = *(const bf16x8*)&w2b[(size_t)((nt * 12 + ks) * 64 + lane) * 8];
      acc[nt] = __builtin_amdgcn_mfma_f32_16x16x32_bf16(af, bfg, acc[nt], 0, 0, 0);
    }
  }

#pragma unroll
  for (int nt = 0; nt < 6; ++nt) {
    int cc = nt * 16 + row;
#pragma unroll
    for (int r = 0; r < 4; ++r)
      tile[cc * 65 + w * 16 + g * 4 + r] = acc[nt][r];
  }
  __syncthreads();
#pragma unroll
  for (int k = 0; k < 24; ++k) {
    int idx = tid + k * 256;
    int cc = idx >> 6, p = idx & 63;
    size_t o = (size_t)(b * 96 + cc) * S3 + sp0 + p;
    out[o] = x[o] + tile[cc * 65 + p] + bias2[cc];
  }
}

// ----------------------------------------------------------------
extern "C" void kernel_launch(void* const* d_in, const int* in_sizes, int n_in,
                              void* d_out, int out_size, void* d_ws, size_t ws_size,
                              hipStream_t stream) {
  const float* x     = (const float*)d_in[0];
  const float* dw_w  = (const float*)d_in[1];
  const float* dw_b  = (const float*)d_in[2];
  const float* ln_w  = (const float*)d_in[3];
  const float* ln_b  = (const float*)d_in[4];
  const float* w1    = (const float*)d_in[5];
  const float* b1    = (const float*)d_in[6];
  const float* grn_w = (const float*)d_in[7];
  const float* grn_b = (const float*)d_in[8];
  const float* w2    = (const float*)d_in[9];
  const float* b2    = (const float*)d_in[10];
  float* out = (float*)d_out;

  char* ws = (char*)d_ws;
  size_t off = 0;
  auto alloc = [&](size_t bytes) -> void* {
    void* p = ws + off;
    off = (off + bytes + 511) & ~(size_t)511;
    return p;
  };
  ushort_t* y   = (ushort_t*)alloc((size_t)2 * 96 * S3 * 2);        // 42.5 MB bf16 conv out
  ushort_t* h   = (ushort_t*)alloc((size_t)221184 * EDIM * 2);      // 170 MB bf16 hidden
  ushort_t* w1p = (ushort_t*)alloc(36864 * 2);
  ushort_t* w2s = (ushort_t*)alloc((size_t)2 * 36864 * 2);
  float* b1f    = (float*)alloc(EDIM * 4);
  float* bias2  = (float*)alloc(CDIM * 4);
  float* sumsq  = (float*)alloc(2 * EDIM * 4);
  float* scale  = (float*)alloc(2 * EDIM * 4);

  hipMemsetAsync(sumsq, 0, 2 * EDIM * 4, stream);
  kprep<<<145, 256, 0, stream>>>(ln_w, ln_b, w1, b1, grn_b, w2, b2, w1p, b1f, bias2);
  kconv<<<6912, 256, 0, stream>>>(x, dw_w, dw_b, y);
  kmlp1<<<3456, 256, 0, stream>>>(y, w1p, b1f, h, sumsq);
  kscale<<<2, 384, 0, stream>>>(sumsq, grn_w, scale);
  kpackw2<<<288, 256, 0, stream>>>(scale, w2, w2s);
  kmlp2<<<3456, 256, 0, stream>>>(h, w2s, bias2, x, out);
}

// Round 3
// 434.968 us; speedup vs baseline: 1.3841x; 1.3313x over previous
//
#include <hip/hip_runtime.h>
#include <hip/hip_bf16.h>
#include <string.h>

#define S3 110592  // 48^3
#define CDIM 96
#define EDIM 384
#define TPAIR 33   // padded bf16-pair stride per tile row (odd -> bank spread)

typedef __attribute__((ext_vector_type(8))) short bf16x8;
typedef __attribute__((ext_vector_type(4))) float f32x4;
typedef unsigned short ushort_t;

__device__ __forceinline__ ushort_t f2bf(float f) {
  __hip_bfloat16 h = __float2bfloat16(f);
  union { __hip_bfloat16 h; ushort_t u; } cv; cv.h = h; return cv.u;
}
__device__ __forceinline__ float bf2f(ushort_t u) {
  union { __hip_bfloat16 h; ushort_t u; } cv; cv.u = u; return __bfloat162float(cv.h);
}
// packed bf16x2 dot product accumulate: d = a.lo*b.lo + a.hi*b.hi + c
__device__ __forceinline__ float dot2bf(unsigned a, unsigned b, float c) {
  float d;
  asm("v_dot2_f32_bf16 %0, %1, %2, %3" : "=v"(d) : "v"(a), "s"(b), "v"(c));
  return d;
}

// ---------------------------------------------------------------- prep: pack w1 (fold ln_w), b1f (fold ln_b), bias2 (fold grn_b via w2)
__global__ void kprep(const float* __restrict__ ln_w, const float* __restrict__ ln_b,
                      const float* __restrict__ w1, const float* __restrict__ b1,
                      const float* __restrict__ grn_b, const float* __restrict__ w2,
                      const float* __restrict__ b2,
                      ushort_t* __restrict__ w1p, float* __restrict__ b1f, float* __restrict__ bias2) {
  int idx = blockIdx.x * 256 + threadIdx.x;
  if (idx < 24 * 3 * 64 * 8) {
    int j = idx & 7, lane = (idx >> 3) & 63, ks = (idx >> 9) % 3, nt = idx / 1536;
    int c = ks * 32 + (lane >> 4) * 8 + j;
    int e = nt * 16 + (lane & 15);
    w1p[idx] = f2bf(ln_w[c] * w1[c * EDIM + e]);
  }
  if (idx < EDIM) {
    float s = b1[idx];
    for (int c = 0; c < CDIM; ++c) s += ln_b[c] * w1[c * EDIM + idx];
    b1f[idx] = s;
  }
  if (idx < CDIM) {
    float s = b2[idx];
    for (int e = 0; e < EDIM; ++e) s += grn_b[e] * w2[e * CDIM + idx];
    bias2[idx] = s;
  }
}

// ---------------------------------------------------------------- pack depthwise weights into dot2 pair tables
// layout: wpk[c*392 + ty*56 + tz*8 + k], k0..3 = even-phase pairs, k4..7 = odd-phase pairs
__global__ void kpackdw(const float* __restrict__ dw_w, unsigned* __restrict__ wpk) {
  int idx = blockIdx.x * 256 + threadIdx.x;
  if (idx >= 96 * 392) return;
  int k = idx & 7; int tz = (idx >> 3) % 7; int ty = (idx / 56) % 7; int cch = idx / 392;
  const float* w = dw_w + ((cch * 7 + tz) * 7 + ty) * 7;  // w[tx], layout [c][kD][kH][kW]
  int m = k & 3;
  float a, b;
  if (k < 4) {  // even outputs: pairs (w0,w1)(w2,w3)(w4,w5)(w6,0)
    a = w[2 * m]; b = (2 * m + 1 < 7) ? w[2 * m + 1] : 0.f;
  } else {      // odd outputs: pairs (0,w0)(w1,w2)(w3,w4)(w5,w6)
    a = (m == 0) ? 0.f : w[2 * m - 1];
    b = w[2 * m];
  }
  wpk[idx] = (unsigned)f2bf(a) | ((unsigned)f2bf(b) << 16);
}

// ---------------------------------------------------------------- depthwise 7x7x7 conv via v_dot2_f32_bf16
// block 256 threads: 8 x-threads (Rx=6), 8 y, 4 z-threads (Rz=2). Tile z=8,y=8,x=48.
// LDS: 14 planes x 14 rows x 33 bf16-pairs = 25.9 KB -> 6 blocks/CU.
__global__ __launch_bounds__(256, 6) void kconv(const float* __restrict__ x,
                                                const unsigned* __restrict__ wpk,
                                                const float* __restrict__ dw_b,
                                                ushort_t* __restrict__ y) {
  __shared__ unsigned tile[14 * 14 * TPAIR];
  int bid = blockIdx.x;
  int yt = bid % 6, zt = (bid / 6) % 6, bc = bid / 36;
  int c = bc % 96;
  int z0 = zt * 8, y0 = yt * 8;
  size_t base = (size_t)bc * S3;
  int tid = threadIdx.x;

  // stage 14x14x27 bf16 pairs (zero-padded halo)
  for (int i = tid; i < 14 * 14 * 27; i += 256) {
    int pc = i % 27; int t = i / 27; int dy = t % 14; int dz = t / 14;
    int gz = z0 - 3 + dz, gy = y0 - 3 + dy, gx0 = 2 * pc - 3;
    float v0 = 0.f, v1 = 0.f;
    if ((unsigned)gz < 48u && (unsigned)gy < 48u) {
      const float* rp = x + base + (size_t)gz * 2304 + gy * 48;
      if ((unsigned)gx0 < 48u) v0 = rp[gx0];
      if ((unsigned)(gx0 + 1) < 48u) v1 = rp[gx0 + 1];
    }
    tile[(dz * 14 + dy) * TPAIR + pc] = (unsigned)f2bf(v0) | ((unsigned)f2bf(v1) << 16);
  }
  __syncthreads();

  int xt = tid & 7, yy = (tid >> 3) & 7, zz = tid >> 6;  // zz in 0..3
  const unsigned* __restrict__ wc = wpk + c * 392;       // block-uniform -> scalar loads

  float acc[2][6];
#pragma unroll
  for (int a = 0; a < 2; ++a)
#pragma unroll
    for (int bI = 0; bI < 6; ++bI) acc[a][bI] = 0.f;

#pragma unroll 1
  for (int ty = 0; ty < 7; ++ty) {
    unsigned wv[56];
#pragma unroll
    for (int i = 0; i < 56; ++i) wv[i] = wc[ty * 56 + i];  // uniform -> SGPR
    int ly = yy + ty;
#pragma unroll
    for (int lp = 0; lp < 8; ++lp) {
      const unsigned* rp = &tile[(((zz << 1) + lp) * 14 + ly) * TPAIR + 3 * xt];
      unsigned P[6];
#pragma unroll
      for (int j = 0; j < 6; ++j) P[j] = rp[j];
#pragma unroll
      for (int zr = 0; zr < 2; ++zr) {
        int tz = lp - zr;
        if (tz >= 0 && tz < 7) {
#pragma unroll
          for (int p = 0; p < 3; ++p) {
#pragma unroll
            for (int m = 0; m < 4; ++m) {
              acc[zr][2 * p]     = dot2bf(P[p + m], wv[tz * 8 + m],     acc[zr][2 * p]);
              acc[zr][2 * p + 1] = dot2bf(P[p + m], wv[tz * 8 + 4 + m], acc[zr][2 * p + 1]);
            }
          }
        }
      }
    }
  }

  float bv = dw_b[c];
#pragma unroll
  for (int zr = 0; zr < 2; ++zr) {
    int z = z0 + (zz << 1) + zr;
    size_t o = base + (size_t)z * 2304 + (size_t)(y0 + yy) * 48 + xt * 6;
#pragma unroll
    for (int xp = 0; xp < 3; ++xp) {
      unsigned pk = ((unsigned)f2bf(acc[zr][2 * xp] + bv)) |
                    ((unsigned)f2bf(acc[zr][2 * xp + 1] + bv) << 16);
      *(unsigned*)&y[o + 2 * xp] = pk;
    }
  }
}

// ---------------------------------------------------------------- LN + GEMM1(96->384) + GELU + sumsq
__global__ __launch_bounds__(256, 2) void kmlp1(const ushort_t* __restrict__ y,
                                                const ushort_t* __restrict__ w1p,
                                                const float* __restrict__ b1f,
                                                ushort_t* __restrict__ h,
                                                float* __restrict__ sumsq) {
  __shared__ ushort_t Al[64 * 104];
  __shared__ float red_s[4][64], red_q[4][64];
  __shared__ float stat_mu[64], stat_rv[64];
  int tid = threadIdx.x;
  int q = tid >> 6, lane = tid & 63;
  size_t pos0 = (size_t)blockIdx.x * 64;
  int b = (int)(pos0 / S3);
  int sp0 = (int)(pos0 % S3);

  float v[24];
  float s = 0.f, ss = 0.f;
  const ushort_t* yb = y + (size_t)b * 96 * S3 + sp0 + lane;
#pragma unroll
  for (int i = 0; i < 24; ++i) {
    int cc = q * 24 + i;
    float f = bf2f(yb[(size_t)cc * S3]);
    v[i] = f; s += f; ss += f * f;
  }
  red_s[q][lane] = s; red_q[q][lane] = ss;
  __syncthreads();
  if (tid < 64) {
    float su = red_s[0][tid] + red_s[1][tid] + red_s[2][tid] + red_s[3][tid];
    float sq = red_q[0][tid] + red_q[1][tid] + red_q[2][tid] + red_q[3][tid];
    float mu = su * (1.f / 96.f);
    float var = sq * (1.f / 96.f) - mu * mu;
    stat_mu[tid] = mu;
    stat_rv[tid] = rsqrtf(var + 1e-6f);
  }
  __syncthreads();
  {
    float mu = stat_mu[lane], rv = stat_rv[lane];
#pragma unroll
    for (int i4 = 0; i4 < 6; ++i4) {
      ushort_t u0 = f2bf((v[i4 * 4 + 0] - mu) * rv);
      ushort_t u1 = f2bf((v[i4 * 4 + 1] - mu) * rv);
      ushort_t u2 = f2bf((v[i4 * 4 + 2] - mu) * rv);
      ushort_t u3 = f2bf((v[i4 * 4 + 3] - mu) * rv);
      uint2 t; t.x = (unsigned)u0 | ((unsigned)u1 << 16); t.y = (unsigned)u2 | ((unsigned)u3 << 16);
      *(uint2*)&Al[lane * 104 + q * 24 + i4 * 4] = t;
    }
  }
  __syncthreads();

  f32x4 acc[4][6];
#pragma unroll
  for (int mt = 0; mt < 4; ++mt)
#pragma unroll
    for (int ntl = 0; ntl < 6; ++ntl) acc[mt][ntl] = (f32x4){0.f, 0.f, 0.f, 0.f};

  int row = lane & 15, g = lane >> 4;
#pragma unroll
  for (int ks = 0; ks < 3; ++ks) {
    bf16x8 af[4];
    int colb = ks * 32 + g * 8;
#pragma unroll
    for (int mt = 0; mt < 4; ++mt)
      af[mt] = *(const bf16x8*)&Al[(mt * 16 + row) * 104 + colb];
#pragma unroll
    for (int ntl = 0; ntl < 6; ++ntl) {
      bf16x8 bfg = *(const bf16x8*)&w1p[(size_t)(((q * 6 + ntl) * 3 + ks) * 64 + lane) * 8];
#pragma unroll
      for (int mt = 0; mt < 4; ++mt)
        acc[mt][ntl] = __builtin_amdgcn_mfma_f32_16x16x32_bf16(af[mt], bfg, acc[mt][ntl], 0, 0, 0);
    }
  }

#pragma unroll
  for (int ntl = 0; ntl < 6; ++ntl) {
    int e = q * 96 + ntl * 16 + row;
    float bb = b1f[e];
    float ssq = 0.f;
#pragma unroll
    for (int mt = 0; mt < 4; ++mt) {
#pragma unroll
      for (int r = 0; r < 4; ++r) {
        float val = acc[mt][ntl][r] + bb;
        float gel = 0.5f * val * (1.f + erff(val * 0.70710678118f));
        size_t p = pos0 + mt * 16 + g * 4 + r;
        h[p * EDIM + e] = f2bf(gel);
        ssq += gel * gel;
      }
    }
    ssq += __shfl_xor(ssq, 16, 64);
    ssq += __shfl_xor(ssq, 32, 64);
    if (g == 0) atomicAdd(&sumsq[b * EDIM + e], ssq);
  }
}

// ---------------------------------------------------------------- GRN scale per (b,e)
__global__ void kscale(const float* __restrict__ sumsq, const float* __restrict__ grn_w,
                       float* __restrict__ scale) {
  __shared__ float wsum[6];
  __shared__ float mean_s;
  int b = blockIdx.x, e = threadIdx.x;  // 384 threads
  float gv = sqrtf(sumsq[b * EDIM + e]);
  float t = gv;
#pragma unroll
  for (int off = 1; off <= 32; off <<= 1) t += __shfl_xor(t, off, 64);
  if ((e & 63) == 0) wsum[e >> 6] = t;
  __syncthreads();
  if (e == 0) {
    float m = 0.f;
    for (int i = 0; i < 6; ++i) m += wsum[i];
    mean_s = m * (1.f / EDIM);
  }
  __syncthreads();
  scale[b * EDIM + e] = grn_w[e] * (gv / (mean_s + 1e-6f)) + 1.f;
}

// ---------------------------------------------------------------- pack scale-folded w2 per batch (MFMA fragment order)
__global__ void kpackw2(const float* __restrict__ scale, const float* __restrict__ w2,
                        ushort_t* __restrict__ w2s) {
  int idx = blockIdx.x * 256 + threadIdx.x;  // exactly 2*36864
  int b = idx / 36864; int r = idx % 36864;
  int j = r & 7, lane = (r >> 3) & 63, ks = (r >> 9) % 12, nt = r / 6144;
  int e = ks * 32 + (lane >> 4) * 8 + j, cc = nt * 16 + (lane & 15);
  w2s[idx] = f2bf(scale[b * EDIM + e] * w2[e * CDIM + cc]);
}

// ---------------------------------------------------------------- GEMM2(384->96) + bias2 + residual, channels-first out
__global__ __launch_bounds__(256, 2) void kmlp2(const ushort_t* __restrict__ h,
                                                const ushort_t* __restrict__ w2s,
                                                const float* __restrict__ bias2,
                                                const float* __restrict__ x,
                                                float* __restrict__ out) {
  __shared__ float tile[96 * 65];
  int tid = threadIdx.x;
  int w = tid >> 6, lane = tid & 63;
  size_t pos0 = (size_t)blockIdx.x * 64;
  int b = (int)(pos0 / S3);
  int sp0 = (int)(pos0 % S3);
  int row = lane & 15, g = lane >> 4;

  f32x4 acc[6];
#pragma unroll
  for (int nt = 0; nt < 6; ++nt) acc[nt] = (f32x4){0.f, 0.f, 0.f, 0.f};

  const ushort_t* w2b = w2s + (size_t)b * 36864;
  size_t abase = (pos0 + w * 16 + row) * (size_t)EDIM + g * 8;
#pragma unroll
  for (int ks = 0; ks < 12; ++ks) {
    bf16x8 af = *(const bf16x8*)&h[abase + ks * 32];
#pragma unroll
    for (int nt = 0; nt < 6; ++nt) {
      bf16x8 bfg = *(const bf16x8*)&w2b[(size_t)((nt * 12 + ks) * 64 + lane) * 8];
      acc[nt] = __builtin_amdgcn_mfma_f32_16x16x32_bf16(af, bfg, acc[nt], 0, 0, 0);
    }
  }

#pragma unroll
  for (int nt = 0; nt < 6; ++nt) {
    int cc = nt * 16 + row;
#pragma unroll
    for (int r = 0; r < 4; ++r)
      tile[cc * 65 + w * 16 + g * 4 + r] = acc[nt][r];
  }
  __syncthreads();
#pragma unroll
  for (int k = 0; k < 24; ++k) {
    int idx = tid + k * 256;
    int cc = idx >> 6, p = idx & 63;
    size_t o = (size_t)(b * 96 + cc) * S3 + sp0 + p;
    out[o] = x[o] + tile[cc * 65 + p] + bias2[cc];
  }
}

// ----------------------------------------------------------------
extern "C" void kernel_launch(void* const* d_in, const int* in_sizes, int n_in,
                              void* d_out, int out_size, void* d_ws, size_t ws_size,
                              hipStream_t stream) {
  const float* x     = (const float*)d_in[0];
  const float* dw_w  = (const float*)d_in[1];
  const float* dw_b  = (const float*)d_in[2];
  const float* ln_w  = (const float*)d_in[3];
  const float* ln_b  = (const float*)d_in[4];
  const float* w1    = (const float*)d_in[5];
  const float* b1    = (const float*)d_in[6];
  const float* grn_w = (const float*)d_in[7];
  const float* grn_b = (const float*)d_in[8];
  const float* w2    = (const float*)d_in[9];
  const float* b2    = (const float*)d_in[10];
  float* out = (float*)d_out;

  char* ws = (char*)d_ws;
  size_t off = 0;
  auto alloc = [&](size_t bytes) -> void* {
    void* p = ws + off;
    off = (off + bytes + 511) & ~(size_t)511;
    return p;
  };
  ushort_t* y   = (ushort_t*)alloc((size_t)2 * 96 * S3 * 2);        // 42.5 MB bf16 conv out
  ushort_t* h   = (ushort_t*)alloc((size_t)221184 * EDIM * 2);      // 170 MB bf16 hidden
  ushort_t* w1p = (ushort_t*)alloc(36864 * 2);
  ushort_t* w2s = (ushort_t*)alloc((size_t)2 * 36864 * 2);
  unsigned* wpk = (unsigned*)alloc(96 * 392 * 4);                   // dot2 weight pairs
  float* b1f    = (float*)alloc(EDIM * 4);
  float* bias2  = (float*)alloc(CDIM * 4);
  float* sumsq  = (float*)alloc(2 * EDIM * 4);
  float* scale  = (float*)alloc(2 * EDIM * 4);

  hipMemsetAsync(sumsq, 0, 2 * EDIM * 4, stream);
  kprep<<<145, 256, 0, stream>>>(ln_w, ln_b, w1, b1, grn_b, w2, b2, w1p, b1f, bias2);
  kpackdw<<<147, 256, 0, stream>>>(dw_w, wpk);
  kconv<<<6912, 256, 0, stream>>>(x, wpk, dw_b, y);
  kmlp1<<<3456, 256, 0, stream>>>(y, w1p, b1f, h, sumsq);
  kscale<<<2, 384, 0, stream>>>(sumsq, grn_w, scale);
  kpackw2<<<288, 256, 0, stream>>>(scale, w2, w2s);
  kmlp2<<<3456, 256, 0, stream>>>(h, w2s, bias2, x, out);
}

// Round 4
// 393.814 us; speedup vs baseline: 1.5287x; 1.1045x over previous
//
#include <hip/hip_runtime.h>
#include <hip/hip_bf16.h>
#include <string.h>

#define S3 110592  // 48^3
#define CDIM 96
#define EDIM 384
#define ZIN 14
#define YIN 22

typedef __attribute__((ext_vector_type(8))) short bf16x8;
typedef __attribute__((ext_vector_type(4))) float f32x4;
typedef unsigned short ushort_t;

__device__ __forceinline__ ushort_t f2bf(float f) {
  __hip_bfloat16 h = __float2bfloat16(f);
  union { __hip_bfloat16 h; ushort_t u; } cv; cv.h = h; return cv.u;
}
__device__ __forceinline__ float bf2f(ushort_t u) {
  union { __hip_bfloat16 h; ushort_t u; } cv; cv.u = u; return __bfloat162float(cv.h);
}

// ---------------------------------------------------------------- prep: pack w1 (fold ln_w), b1f (fold ln_b), bias2 (fold grn_b via w2)
__global__ void kprep(const float* __restrict__ ln_w, const float* __restrict__ ln_b,
                      const float* __restrict__ w1, const float* __restrict__ b1,
                      const float* __restrict__ grn_b, const float* __restrict__ w2,
                      const float* __restrict__ b2,
                      ushort_t* __restrict__ w1p, float* __restrict__ b1f, float* __restrict__ bias2) {
  int idx = blockIdx.x * 256 + threadIdx.x;
  if (idx < 24 * 3 * 64 * 8) {
    int j = idx & 7, lane = (idx >> 3) & 63, ks = (idx >> 9) % 3, nt = idx / 1536;
    int c = ks * 32 + (lane >> 4) * 8 + j;
    int e = nt * 16 + (lane & 15);
    w1p[idx] = f2bf(ln_w[c] * w1[c * EDIM + e]);
  }
  if (idx < EDIM) {
    float s = b1[idx];
    for (int c = 0; c < CDIM; ++c) s += ln_b[c] * w1[c * EDIM + idx];
    b1f[idx] = s;
  }
  if (idx < CDIM) {
    float s = b2[idx];
    for (int e = 0; e < EDIM; ++e) s += grn_b[e] * w2[e * CDIM + idx];
    bias2[idx] = s;
  }
}

// ---------------------------------------------------------------- pack depthwise weights as banded-Toeplitz MFMA B-fragments
// Btab[c][t=tz*7+ty][lane*8+j] = B[k][n], k=(lane>>4)*8+j, n=lane&15, B[k][n]=w[tz][ty][k-n] if 0<=k-n<7 else 0
__global__ void kpackB(const float* __restrict__ dw_w, ushort_t* __restrict__ Btab) {
  int idx = blockIdx.x * 256 + threadIdx.x;
  if (idx >= 96 * 49 * 512) return;
  int pos = idx & 511; int t = (idx >> 9) % 49; int c = idx / (49 * 512);
  int lane = pos >> 3, j = pos & 7;
  int k = (lane >> 4) * 8 + j, n = lane & 15;
  int tx = k - n;
  int tz = t / 7, ty = t % 7;
  float v = (tx >= 0 && tx < 7) ? dw_w[c * 343 + tz * 49 + ty * 7 + tx] : 0.f;
  Btab[idx] = f2bf(v);
}

// ---------------------------------------------------------------- depthwise 7x7x7 conv on the MATRIX pipe
// 192 threads = 3 waves; wave = x-tile (16 outputs). Block tile: z=8, y=16, x=48.
// LDS: 14 z-planes x 22 y-rows x 64 x-entries bf16 (x in [-3,61), zero-padded) = 39.4 KB -> 4 blocks/CU.
// One A-frag (z-plane slab) feeds up to 7 MFMA (tz taps) into different z-out accumulators: 4x LDS reuse.
__global__ __launch_bounds__(192, 3) void kconv(const float* __restrict__ x,
                                                const ushort_t* __restrict__ Btab,
                                                const float* __restrict__ dw_b,
                                                ushort_t* __restrict__ y) {
  __shared__ unsigned tile[ZIN * YIN * 32];  // pairs of bf16, 16B-unit XOR swizzle by (row&7)
  int bid = blockIdx.x;
  int yt = bid % 3, zt = (bid / 3) % 6, bc = bid / 18;  // 2*96*6*3 = 3456 blocks
  int c = bc % 96;
  int z0 = zt * 8, y0 = yt * 16;
  size_t base = (size_t)bc * S3;
  int tid = threadIdx.x;

  // stage: row = dz*22+dy, pair pc covers x = 2pc-3, 2pc-2; swizzled word = pc ^ ((row&7)<<2)
  for (int i = tid; i < ZIN * YIN * 32; i += 192) {
    int pc = i & 31; int row = i >> 5; int dy = row % YIN; int dz = row / YIN;
    int gz = z0 - 3 + dz, gy = y0 - 3 + dy, gx0 = 2 * pc - 3;
    float v0 = 0.f, v1 = 0.f;
    if ((unsigned)gz < 48u && (unsigned)gy < 48u) {
      const float* rp = x + base + (size_t)gz * 2304 + gy * 48;
      if ((unsigned)gx0 < 48u) v0 = rp[gx0];
      if ((unsigned)(gx0 + 1) < 48u) v1 = rp[gx0 + 1];
    }
    tile[(row << 5) + (pc ^ ((row & 7) << 2))] = (unsigned)f2bf(v0) | ((unsigned)f2bf(v1) << 16);
  }
  __syncthreads();

  int X = tid / 64;          // wave's x-tile: outputs X*16 .. X*16+15
  int lane = tid & 63;
  int am = lane & 15, g = lane >> 4;   // A-row lane index, k-slot group
  int xg = X * 32 + g * 16;            // byte offset of k-window within row (before swizzle)

  f32x4 acc[8];
#pragma unroll
  for (int p = 0; p < 8; ++p) acc[p] = (f32x4){0.f, 0.f, 0.f, 0.f};

  const ushort_t* __restrict__ Bt = Btab + (size_t)c * 49 * 512;

#pragma unroll 1
  for (int ty = 0; ty < 7; ++ty) {
    bf16x8 bfr[7];
#pragma unroll
    for (int tz = 0; tz < 7; ++tz)
      bfr[tz] = *(const bf16x8*)&Bt[(tz * 7 + ty) * 512 + lane * 8];
    int rowbase = am + ty;  // y-input row within plane
#pragma unroll
    for (int zl = 0; zl < 14; ++zl) {
      int row = zl * YIN + rowbase;
      int byteoff = (row << 7) + (xg ^ ((row & 7) << 4));
      bf16x8 af = *(const bf16x8*)((const char*)tile + byteoff);
#pragma unroll
      for (int tz = 0; tz < 7; ++tz) {
        if (zl - tz >= 0 && zl - tz < 8)  // compile-time after unroll
          acc[zl - tz] = __builtin_amdgcn_mfma_f32_16x16x32_bf16(af, bfr[tz], acc[zl - tz], 0, 0, 0);
      }
    }
  }

  // D layout: n = lane&15 -> x offset; m = g*4+r -> y offset
  float bv = dw_b[c];
#pragma unroll
  for (int p = 0; p < 8; ++p) {
    size_t zb = base + (size_t)(z0 + p) * 2304;
#pragma unroll
    for (int r = 0; r < 4; ++r) {
      int yo = y0 + g * 4 + r;
      y[zb + yo * 48 + X * 16 + am] = f2bf(acc[p][r] + bv);
    }
  }
}

// ---------------------------------------------------------------- LN + GEMM1(96->384) + GELU + sumsq
__global__ __launch_bounds__(256, 2) void kmlp1(const ushort_t* __restrict__ y,
                                                const ushort_t* __restrict__ w1p,
                                                const float* __restrict__ b1f,
                                                ushort_t* __restrict__ h,
                                                float* __restrict__ sumsq) {
  __shared__ ushort_t Al[64 * 104];
  __shared__ float red_s[4][64], red_q[4][64];
  __shared__ float stat_mu[64], stat_rv[64];
  int tid = threadIdx.x;
  int q = tid >> 6, lane = tid & 63;
  size_t pos0 = (size_t)blockIdx.x * 64;
  int b = (int)(pos0 / S3);
  int sp0 = (int)(pos0 % S3);

  float v[24];
  float s = 0.f, ss = 0.f;
  const ushort_t* yb = y + (size_t)b * 96 * S3 + sp0 + lane;
#pragma unroll
  for (int i = 0; i < 24; ++i) {
    int cc = q * 24 + i;
    float f = bf2f(yb[(size_t)cc * S3]);
    v[i] = f; s += f; ss += f * f;
  }
  red_s[q][lane] = s; red_q[q][lane] = ss;
  __syncthreads();
  if (tid < 64) {
    float su = red_s[0][tid] + red_s[1][tid] + red_s[2][tid] + red_s[3][tid];
    float sq = red_q[0][tid] + red_q[1][tid] + red_q[2][tid] + red_q[3][tid];
    float mu = su * (1.f / 96.f);
    float var = sq * (1.f / 96.f) - mu * mu;
    stat_mu[tid] = mu;
    stat_rv[tid] = rsqrtf(var + 1e-6f);
  }
  __syncthreads();
  {
    float mu = stat_mu[lane], rv = stat_rv[lane];
#pragma unroll
    for (int i4 = 0; i4 < 6; ++i4) {
      ushort_t u0 = f2bf((v[i4 * 4 + 0] - mu) * rv);
      ushort_t u1 = f2bf((v[i4 * 4 + 1] - mu) * rv);
      ushort_t u2 = f2bf((v[i4 * 4 + 2] - mu) * rv);
      ushort_t u3 = f2bf((v[i4 * 4 + 3] - mu) * rv);
      uint2 t; t.x = (unsigned)u0 | ((unsigned)u1 << 16); t.y = (unsigned)u2 | ((unsigned)u3 << 16);
      *(uint2*)&Al[lane * 104 + q * 24 + i4 * 4] = t;
    }
  }
  __syncthreads();

  f32x4 acc[4][6];
#pragma unroll
  for (int mt = 0; mt < 4; ++mt)
#pragma unroll
    for (int ntl = 0; ntl < 6; ++ntl) acc[mt][ntl] = (f32x4){0.f, 0.f, 0.f, 0.f};

  int row = lane & 15, g = lane >> 4;
#pragma unroll
  for (int ks = 0; ks < 3; ++ks) {
    bf16x8 af[4];
    int colb = ks * 32 + g * 8;
#pragma unroll
    for (int mt = 0; mt < 4; ++mt)
      af[mt] = *(const bf16x8*)&Al[(mt * 16 + row) * 104 + colb];
#pragma unroll
    for (int ntl = 0; ntl < 6; ++ntl) {
      bf16x8 bfg = *(const bf16x8*)&w1p[(size_t)(((q * 6 + ntl) * 3 + ks) * 64 + lane) * 8];
#pragma unroll
      for (int mt = 0; mt < 4; ++mt)
        acc[mt][ntl] = __builtin_amdgcn_mfma_f32_16x16x32_bf16(af[mt], bfg, acc[mt][ntl], 0, 0, 0);
    }
  }

#pragma unroll
  for (int ntl = 0; ntl < 6; ++ntl) {
    int e = q * 96 + ntl * 16 + row;
    float bb = b1f[e];
    float ssq = 0.f;
#pragma unroll
    for (int mt = 0; mt < 4; ++mt) {
#pragma unroll
      for (int r = 0; r < 4; ++r) {
        float val = acc[mt][ntl][r] + bb;
        float gel = 0.5f * val * (1.f + erff(val * 0.70710678118f));
        size_t p = pos0 + mt * 16 + g * 4 + r;
        h[p * EDIM + e] = f2bf(gel);
        ssq += gel * gel;
      }
    }
    ssq += __shfl_xor(ssq, 16, 64);
    ssq += __shfl_xor(ssq, 32, 64);
    if (g == 0) atomicAdd(&sumsq[b * EDIM + e], ssq);
  }
}

// ---------------------------------------------------------------- GRN scale per (b,e)
__global__ void kscale(const float* __restrict__ sumsq, const float* __restrict__ grn_w,
                       float* __restrict__ scale) {
  __shared__ float wsum[6];
  __shared__ float mean_s;
  int b = blockIdx.x, e = threadIdx.x;  // 384 threads
  float gv = sqrtf(sumsq[b * EDIM + e]);
  float t = gv;
#pragma unroll
  for (int off = 1; off <= 32; off <<= 1) t += __shfl_xor(t, off, 64);
  if ((e & 63) == 0) wsum[e >> 6] = t;
  __syncthreads();
  if (e == 0) {
    float m = 0.f;
    for (int i = 0; i < 6; ++i) m += wsum[i];
    mean_s = m * (1.f / EDIM);
  }
  __syncthreads();
  scale[b * EDIM + e] = grn_w[e] * (gv / (mean_s + 1e-6f)) + 1.f;
}

// ---------------------------------------------------------------- pack scale-folded w2 per batch (MFMA fragment order)
__global__ void kpackw2(const float* __restrict__ scale, const float* __restrict__ w2,
                        ushort_t* __restrict__ w2s) {
  int idx = blockIdx.x * 256 + threadIdx.x;  // exactly 2*36864
  int b = idx / 36864; int r = idx % 36864;
  int j = r & 7, lane = (r >> 3) & 63, ks = (r >> 9) % 12, nt = r / 6144;
  int e = ks * 32 + (lane >> 4) * 8 + j, cc = nt * 16 + (lane & 15);
  w2s[idx] = f2bf(scale[b * EDIM + e] * w2[e * CDIM + cc]);
}

// ---------------------------------------------------------------- GEMM2(384->96) + bias2 + residual, channels-first out
__global__ __launch_bounds__(256, 2) void kmlp2(const ushort_t* __restrict__ h,
                                                const ushort_t* __restrict__ w2s,
                                                const float* __restrict__ bias2,
                                                const float* __restrict__ x,
                                                float* __restrict__ out) {
  __shared__ float tile[96 * 65];
  int tid = threadIdx.x;
  int w = tid >> 6, lane = tid & 63;
  size_t pos0 = (size_t)blockIdx.x * 64;
  int b = (int)(pos0 / S3);
  int sp0 = (int)(pos0 % S3);
  int row = lane & 15, g = lane >> 4;

  f32x4 acc[6];
#pragma unroll
  for (int nt = 0; nt < 6; ++nt) acc[nt] = (f32x4){0.f, 0.f, 0.f, 0.f};

  const ushort_t* w2b = w2s + (size_t)b * 36864;
  size_t abase = (pos0 + w * 16 + row) * (size_t)EDIM + g * 8;
#pragma unroll
  for (int ks = 0; ks < 12; ++ks) {
    bf16x8 af = *(const bf16x8*)&h[abase + ks * 32];
#pragma unroll
    for (int nt = 0; nt < 6; ++nt) {
      bf16x8 bfg = *(const bf16x8*)&w2b[(size_t)((nt * 12 + ks) * 64 + lane) * 8];
      acc[nt] = __builtin_amdgcn_mfma_f32_16x16x32_bf16(af, bfg, acc[nt], 0, 0, 0);
    }
  }

#pragma unroll
  for (int nt = 0; nt < 6; ++nt) {
    int cc = nt * 16 + row;
#pragma unroll
    for (int r = 0; r < 4; ++r)
      tile[cc * 65 + w * 16 + g * 4 + r] = acc[nt][r];
  }
  __syncthreads();
#pragma unroll
  for (int k = 0; k < 24; ++k) {
    int idx = tid + k * 256;
    int cc = idx >> 6, p = idx & 63;
    size_t o = (size_t)(b * 96 + cc) * S3 + sp0 + p;
    out[o] = x[o] + tile[cc * 65 + p] + bias2[cc];
  }
}

// ----------------------------------------------------------------
extern "C" void kernel_launch(void* const* d_in, const int* in_sizes, int n_in,
                              void* d_out, int out_size, void* d_ws, size_t ws_size,
                              hipStream_t stream) {
  const float* x     = (const float*)d_in[0];
  const float* dw_w  = (const float*)d_in[1];
  const float* dw_b  = (const float*)d_in[2];
  const float* ln_w  = (const float*)d_in[3];
  const float* ln_b  = (const float*)d_in[4];
  const float* w1    = (const float*)d_in[5];
  const float* b1    = (const float*)d_in[6];
  const float* grn_w = (const float*)d_in[7];
  const float* grn_b = (const float*)d_in[8];
  const float* w2    = (const float*)d_in[9];
  const float* b2    = (const float*)d_in[10];
  float* out = (float*)d_out;

  char* ws = (char*)d_ws;
  size_t off = 0;
  auto alloc = [&](size_t bytes) -> void* {
    void* p = ws + off;
    off = (off + bytes + 511) & ~(size_t)511;
    return p;
  };
  ushort_t* y    = (ushort_t*)alloc((size_t)2 * 96 * S3 * 2);        // 42.5 MB bf16 conv out
  ushort_t* h    = (ushort_t*)alloc((size_t)221184 * EDIM * 2);      // 170 MB bf16 hidden
  ushort_t* w1p  = (ushort_t*)alloc(36864 * 2);
  ushort_t* w2s  = (ushort_t*)alloc((size_t)2 * 36864 * 2);
  ushort_t* Btab = (ushort_t*)alloc((size_t)96 * 49 * 512 * 2);      // 4.8 MB Toeplitz B-frags
  float* b1f     = (float*)alloc(EDIM * 4);
  float* bias2   = (float*)alloc(CDIM * 4);
  float* sumsq   = (float*)alloc(2 * EDIM * 4);
  float* scale   = (float*)alloc(2 * EDIM * 4);

  hipMemsetAsync(sumsq, 0, 2 * EDIM * 4, stream);
  kprep<<<145, 256, 0, stream>>>(ln_w, ln_b, w1, b1, grn_b, w2, b2, w1p, b1f, bias2);
  kpackB<<<9408, 256, 0, stream>>>(dw_w, Btab);
  kconv<<<3456, 192, 0, stream>>>(x, Btab, dw_b, y);
  kmlp1<<<3456, 256, 0, stream>>>(y, w1p, b1f, h, sumsq);
  kscale<<<2, 384, 0, stream>>>(sumsq, grn_w, scale);
  kpackw2<<<288, 256, 0, stream>>>(scale, w2, w2s);
  kmlp2<<<3456, 256, 0, stream>>>(h, w2s, bias2, x, out);
}

// Round 5
// 363.147 us; speedup vs baseline: 1.6578x; 1.0844x over previous
//
#include <hip/hip_runtime.h>
#include <hip/hip_bf16.h>
#include <string.h>

#define S3 110592  // 48^3
#define CDIM 96
#define EDIM 384
#define ZIN 14
#define YIN 22

typedef __attribute__((ext_vector_type(8))) short bf16x8;
typedef __attribute__((ext_vector_type(4))) float f32x4;
typedef unsigned short ushort_t;

__device__ __forceinline__ ushort_t f2bf(float f) {
  __hip_bfloat16 h = __float2bfloat16(f);
  union { __hip_bfloat16 h; ushort_t u; } cv; cv.h = h; return cv.u;
}
__device__ __forceinline__ float bf2f(ushort_t u) {
  union { __hip_bfloat16 h; ushort_t u; } cv; cv.u = u; return __bfloat162float(cv.h);
}

// ---------------------------------------------------------------- prep: pack w1 (fold ln_w), b1f (fold ln_b), bias2 (fold grn_b via w2)
__global__ void kprep(const float* __restrict__ ln_w, const float* __restrict__ ln_b,
                      const float* __restrict__ w1, const float* __restrict__ b1,
                      const float* __restrict__ grn_b, const float* __restrict__ w2,
                      const float* __restrict__ b2,
                      ushort_t* __restrict__ w1p, float* __restrict__ b1f, float* __restrict__ bias2) {
  int idx = blockIdx.x * 256 + threadIdx.x;
  if (idx < 24 * 3 * 64 * 8) {
    int j = idx & 7, lane = (idx >> 3) & 63, ks = (idx >> 9) % 3, nt = idx / 1536;
    int c = ks * 32 + (lane >> 4) * 8 + j;
    int e = nt * 16 + (lane & 15);
    w1p[idx] = f2bf(ln_w[c] * w1[c * EDIM + e]);
  }
  if (idx < EDIM) {
    float s = b1[idx];
    for (int c = 0; c < CDIM; ++c) s += ln_b[c] * w1[c * EDIM + idx];
    b1f[idx] = s;
  }
  if (idx < CDIM) {
    float s = b2[idx];
    for (int e = 0; e < EDIM; ++e) s += grn_b[e] * w2[e * CDIM + idx];
    bias2[idx] = s;
  }
}

// ---------------------------------------------------------------- pack depthwise weights as banded-Toeplitz MFMA B-fragments
// Btab[c][t=tz*7+ty][lane*8+j] = B[k][n], k=(lane>>4)*8+j, n=lane&15, B[k][n]=w[tz][ty][k-n] if 0<=k-n<7 else 0
__global__ void kpackB(const float* __restrict__ dw_w, ushort_t* __restrict__ Btab) {
  int idx = blockIdx.x * 256 + threadIdx.x;
  if (idx >= 96 * 49 * 512) return;
  int pos = idx & 511; int t = (idx >> 9) % 49; int c = idx / (49 * 512);
  int lane = pos >> 3, j = pos & 7;
  int k = (lane >> 4) * 8 + j, n = lane & 15;
  int tx = k - n;
  int tz = t / 7, ty = t % 7;
  float v = (tx >= 0 && tx < 7) ? dw_w[c * 343 + tz * 49 + ty * 7 + tx] : 0.f;
  Btab[idx] = f2bf(v);
}

// ---------------------------------------------------------------- depthwise conv MFMA compute (templated zl-half; all acc indices compile-time)
template<int HALF>
__device__ __forceinline__ void conv_ty_loop(const unsigned* tile, const ushort_t* Bt,
                                             int lane, int am, int xg, f32x4* acc) {
#pragma unroll 1
  for (int ty = 0; ty < 7; ++ty) {
    bf16x8 bfr[7];
#pragma unroll
    for (int tz = 0; tz < 7; ++tz)
      bfr[tz] = *(const bf16x8*)&Bt[(tz * 7 + ty) * 512 + lane * 8];
    int rowbase = am + ty;
#pragma unroll
    for (int zl = 0; zl < 7; ++zl) {
      int row = (HALF * 7 + zl) * YIN + rowbase;
      int byteoff = (row << 7) + (xg ^ ((row & 7) << 4));
      bf16x8 af = *(const bf16x8*)((const char*)tile + byteoff);
#pragma unroll
      for (int tz = 0; tz < 7; ++tz) {
        int l = (HALF == 0) ? (zl - tz) : (zl + 6 - tz);
        if (l >= 0 && l < 7)  // compile-time after unroll
          acc[l] = __builtin_amdgcn_mfma_f32_16x16x32_bf16(af, bfr[tz], acc[l], 0, 0, 0);
      }
    }
  }
}

// ---------------------------------------------------------------- depthwise 7x7x7 conv on the MATRIX pipe
// 384 threads = 6 waves: wave = (half = zl-range, X = x-tile). Block tile: z=8, y=16, x=48.
// LDS: 14 z-planes x 22 y-rows x 64 x-entries bf16, 16B-unit XOR swizzle = 39.4 KB -> 4 blocks/CU.
// half0 covers input planes 0-6 (out p=0..6 partial), half1 planes 7-13 (p=1..7 partial);
// overlap p=1..6 reduced through LDS (tile reused as f32 scratch, row stride 50 -> <=2-way).
__global__ __launch_bounds__(384, 6) void kconv(const float* __restrict__ x,
                                                const ushort_t* __restrict__ Btab,
                                                const float* __restrict__ dw_b,
                                                ushort_t* __restrict__ y) {
  __shared__ unsigned tile[ZIN * YIN * 32];
  int bid = blockIdx.x;
  int yt = bid % 3, zt = (bid / 3) % 6, bc = bid / 18;  // 2*96*6*3 = 3456 blocks
  int c = bc % 96;
  int z0 = zt * 8, y0 = yt * 16;
  size_t base = (size_t)bc * S3;
  int tid = threadIdx.x;

  // stage: row = dz*22+dy, pair pc covers x = 2pc-3, 2pc-2; swizzled word = pc ^ ((row&7)<<2)
  for (int i = tid; i < ZIN * YIN * 32; i += 384) {
    int pc = i & 31; int row = i >> 5; int dy = row % YIN; int dz = row / YIN;
    int gz = z0 - 3 + dz, gy = y0 - 3 + dy, gx0 = 2 * pc - 3;
    float v0 = 0.f, v1 = 0.f;
    if ((unsigned)gz < 48u && (unsigned)gy < 48u) {
      const float* rp = x + base + (size_t)gz * 2304 + gy * 48;
      if ((unsigned)gx0 < 48u) v0 = rp[gx0];
      if ((unsigned)(gx0 + 1) < 48u) v1 = rp[gx0 + 1];
    }
    tile[(row << 5) + (pc ^ ((row & 7) << 2))] = (unsigned)f2bf(v0) | ((unsigned)f2bf(v1) << 16);
  }
  __syncthreads();

  int w = tid >> 6;
  int X = w % 3, half = w / 3;
  int lane = tid & 63;
  int am = lane & 15, g = lane >> 4;
  int xg = X * 32 + g * 16;  // byte offset of k-window within row (before swizzle)

  f32x4 acc[7];
#pragma unroll
  for (int p = 0; p < 7; ++p) acc[p] = (f32x4){0.f, 0.f, 0.f, 0.f};

  const ushort_t* __restrict__ Bt = Btab + (size_t)c * 49 * 512;
  if (half == 0) conv_ty_loop<0>(tile, Bt, lane, am, xg, acc);
  else           conv_ty_loop<1>(tile, Bt, lane, am, xg, acc);

  float bv = dw_b[c];
  float* red = (float*)tile;
  int rcol = X * 16 + am;
  __syncthreads();  // all tile reads done -> reuse as f32 scratch
  if (half == 0) {
#pragma unroll
    for (int l = 1; l < 7; ++l)
#pragma unroll
      for (int r = 0; r < 4; ++r)
        red[(l - 1) * 800 + (g * 4 + r) * 50 + rcol] = acc[l][r];
  }
  __syncthreads();
  if (half == 0) {
    size_t zb = base + (size_t)z0 * 2304;
#pragma unroll
    for (int r = 0; r < 4; ++r)
      y[zb + (size_t)(y0 + g * 4 + r) * 48 + rcol] = f2bf(acc[0][r] + bv);
  } else {
#pragma unroll
    for (int l = 0; l < 7; ++l) {
      size_t zb = base + (size_t)(z0 + l + 1) * 2304;
#pragma unroll
      for (int r = 0; r < 4; ++r) {
        float v = acc[l][r] + bv;
        if (l < 6) v += red[l * 800 + (g * 4 + r) * 50 + rcol];
        y[zb + (size_t)(y0 + g * 4 + r) * 48 + rcol] = f2bf(v);
      }
    }
  }
}

// ---------------------------------------------------------------- LN + GEMM1(96->384) + GELU + sumsq
// 512 threads = 8 waves; wave q owns e-range [q*48, q*48+48); 64 positions per block
__global__ __launch_bounds__(512, 4) void kmlp1(const ushort_t* __restrict__ y,
                                                const ushort_t* __restrict__ w1p,
                                                const float* __restrict__ b1f,
                                                ushort_t* __restrict__ h,
                                                float* __restrict__ sumsq) {
  __shared__ ushort_t Al[64 * 104];
  __shared__ float red_s[8][64], red_q[8][64];
  __shared__ float stat_mu[64], stat_rv[64];
  int tid = threadIdx.x;
  int q = tid >> 6, lane = tid & 63;
  size_t pos0 = (size_t)blockIdx.x * 64;
  int b = (int)(pos0 / S3);
  int sp0 = (int)(pos0 % S3);

  float v[12];
  float s = 0.f, ss = 0.f;
  const ushort_t* yb = y + (size_t)b * 96 * S3 + sp0 + lane;
#pragma unroll
  for (int i = 0; i < 12; ++i) {
    float f = bf2f(yb[(size_t)(q * 12 + i) * S3]);
    v[i] = f; s += f; ss += f * f;
  }
  red_s[q][lane] = s; red_q[q][lane] = ss;
  __syncthreads();
  if (tid < 64) {
    float su = 0.f, sq = 0.f;
#pragma unroll
    for (int k = 0; k < 8; ++k) { su += red_s[k][tid]; sq += red_q[k][tid]; }
    float mu = su * (1.f / 96.f);
    float var = sq * (1.f / 96.f) - mu * mu;
    stat_mu[tid] = mu;
    stat_rv[tid] = rsqrtf(var + 1e-6f);
  }
  __syncthreads();
  {
    float mu = stat_mu[lane], rv = stat_rv[lane];
#pragma unroll
    for (int i4 = 0; i4 < 3; ++i4) {
      ushort_t u0 = f2bf((v[i4 * 4 + 0] - mu) * rv);
      ushort_t u1 = f2bf((v[i4 * 4 + 1] - mu) * rv);
      ushort_t u2 = f2bf((v[i4 * 4 + 2] - mu) * rv);
      ushort_t u3 = f2bf((v[i4 * 4 + 3] - mu) * rv);
      uint2 t; t.x = (unsigned)u0 | ((unsigned)u1 << 16); t.y = (unsigned)u2 | ((unsigned)u3 << 16);
      *(uint2*)&Al[lane * 104 + q * 12 + i4 * 4] = t;
    }
  }
  __syncthreads();

  f32x4 acc[4][3];
#pragma unroll
  for (int mt = 0; mt < 4; ++mt)
#pragma unroll
    for (int ntl = 0; ntl < 3; ++ntl) acc[mt][ntl] = (f32x4){0.f, 0.f, 0.f, 0.f};

  int row = lane & 15, g = lane >> 4;
#pragma unroll
  for (int ks = 0; ks < 3; ++ks) {
    bf16x8 af[4];
    int colb = ks * 32 + g * 8;
#pragma unroll
    for (int mt = 0; mt < 4; ++mt)
      af[mt] = *(const bf16x8*)&Al[(mt * 16 + row) * 104 + colb];
#pragma unroll
    for (int ntl = 0; ntl < 3; ++ntl) {
      bf16x8 bfg = *(const bf16x8*)&w1p[(size_t)(((q * 3 + ntl) * 3 + ks) * 64 + lane) * 8];
#pragma unroll
      for (int mt = 0; mt < 4; ++mt)
        acc[mt][ntl] = __builtin_amdgcn_mfma_f32_16x16x32_bf16(af[mt], bfg, acc[mt][ntl], 0, 0, 0);
    }
  }

#pragma unroll
  for (int ntl = 0; ntl < 3; ++ntl) {
    int e = q * 48 + ntl * 16 + row;
    float bb = b1f[e];
    float ssq = 0.f;
#pragma unroll
    for (int mt = 0; mt < 4; ++mt) {
#pragma unroll
      for (int r = 0; r < 4; ++r) {
        float val = acc[mt][ntl][r] + bb;
        float gel = 0.5f * val * (1.f + erff(val * 0.70710678118f));
        size_t p = pos0 + mt * 16 + g * 4 + r;
        h[p * EDIM + e] = f2bf(gel);
        ssq += gel * gel;
      }
    }
    ssq += __shfl_xor(ssq, 16, 64);
    ssq += __shfl_xor(ssq, 32, 64);
    if (g == 0) atomicAdd(&sumsq[b * EDIM + e], ssq);
  }
}

// ---------------------------------------------------------------- GRN scale per (b,e)
__global__ void kscale(const float* __restrict__ sumsq, const float* __restrict__ grn_w,
                       float* __restrict__ scale) {
  __shared__ float wsum[6];
  __shared__ float mean_s;
  int b = blockIdx.x, e = threadIdx.x;  // 384 threads
  float gv = sqrtf(sumsq[b * EDIM + e]);
  float t = gv;
#pragma unroll
  for (int off = 1; off <= 32; off <<= 1) t += __shfl_xor(t, off, 64);
  if ((e & 63) == 0) wsum[e >> 6] = t;
  __syncthreads();
  if (e == 0) {
    float m = 0.f;
    for (int i = 0; i < 6; ++i) m += wsum[i];
    mean_s = m * (1.f / EDIM);
  }
  __syncthreads();
  scale[b * EDIM + e] = grn_w[e] * (gv / (mean_s + 1e-6f)) + 1.f;
}

// ---------------------------------------------------------------- pack scale-folded w2 per batch (MFMA fragment order)
__global__ void kpackw2(const float* __restrict__ scale, const float* __restrict__ w2,
                        ushort_t* __restrict__ w2s) {
  int idx = blockIdx.x * 256 + threadIdx.x;  // exactly 2*36864
  int b = idx / 36864; int r = idx % 36864;
  int j = r & 7, lane = (r >> 3) & 63, ks = (r >> 9) % 12, nt = r / 6144;
  int e = ks * 32 + (lane >> 4) * 8 + j, cc = nt * 16 + (lane & 15);
  w2s[idx] = f2bf(scale[b * EDIM + e] * w2[e * CDIM + cc]);
}

// ---------------------------------------------------------------- GEMM2(384->96) + bias2 + residual, channels-first out
__global__ __launch_bounds__(256, 2) void kmlp2(const ushort_t* __restrict__ h,
                                                const ushort_t* __restrict__ w2s,
                                                const float* __restrict__ bias2,
                                                const float* __restrict__ x,
                                                float* __restrict__ out) {
  __shared__ float tile[96 * 65];
  int tid = threadIdx.x;
  int w = tid >> 6, lane = tid & 63;
  size_t pos0 = (size_t)blockIdx.x * 64;
  int b = (int)(pos0 / S3);
  int sp0 = (int)(pos0 % S3);
  int row = lane & 15, g = lane >> 4;

  f32x4 acc[6];
#pragma unroll
  for (int nt = 0; nt < 6; ++nt) acc[nt] = (f32x4){0.f, 0.f, 0.f, 0.f};

  const ushort_t* w2b = w2s + (size_t)b * 36864;
  size_t abase = (pos0 + w * 16 + row) * (size_t)EDIM + g * 8;
#pragma unroll
  for (int ks = 0; ks < 12; ++ks) {
    bf16x8 af = *(const bf16x8*)&h[abase + ks * 32];
#pragma unroll
    for (int nt = 0; nt < 6; ++nt) {
      bf16x8 bfg = *(const bf16x8*)&w2b[(size_t)((nt * 12 + ks) * 64 + lane) * 8];
      acc[nt] = __builtin_amdgcn_mfma_f32_16x16x32_bf16(af, bfg, acc[nt], 0, 0, 0);
    }
  }

#pragma unroll
  for (int nt = 0; nt < 6; ++nt) {
    int cc = nt * 16 + row;
#pragma unroll
    for (int r = 0; r < 4; ++r)
      tile[cc * 65 + w * 16 + g * 4 + r] = acc[nt][r];
  }
  __syncthreads();
#pragma unroll
  for (int k = 0; k < 24; ++k) {
    int idx = tid + k * 256;
    int cc = idx >> 6, p = idx & 63;
    size_t o = (size_t)(b * 96 + cc) * S3 + sp0 + p;
    out[o] = x[o] + tile[cc * 65 + p] + bias2[cc];
  }
}

// ----------------------------------------------------------------
extern "C" void kernel_launch(void* const* d_in, const int* in_sizes, int n_in,
                              void* d_out, int out_size, void* d_ws, size_t ws_size,
                              hipStream_t stream) {
  const float* x     = (const float*)d_in[0];
  const float* dw_w  = (const float*)d_in[1];
  const float* dw_b  = (const float*)d_in[2];
  const float* ln_w  = (const float*)d_in[3];
  const float* ln_b  = (const float*)d_in[4];
  const float* w1    = (const float*)d_in[5];
  const float* b1    = (const float*)d_in[6];
  const float* grn_w = (const float*)d_in[7];
  const float* grn_b = (const float*)d_in[8];
  const float* w2    = (const float*)d_in[9];
  const float* b2    = (const float*)d_in[10];
  float* out = (float*)d_out;

  char* ws = (char*)d_ws;
  size_t off = 0;
  auto alloc = [&](size_t bytes) -> void* {
    void* p = ws + off;
    off = (off + bytes + 511) & ~(size_t)511;
    return p;
  };
  ushort_t* y    = (ushort_t*)alloc((size_t)2 * 96 * S3 * 2);        // 42.5 MB bf16 conv out
  ushort_t* h    = (ushort_t*)alloc((size_t)221184 * EDIM * 2);      // 170 MB bf16 hidden
  ushort_t* w1p  = (ushort_t*)alloc(36864 * 2);
  ushort_t* w2s  = (ushort_t*)alloc((size_t)2 * 36864 * 2);
  ushort_t* Btab = (ushort_t*)alloc((size_t)96 * 49 * 512 * 2);      // 4.8 MB Toeplitz B-frags
  float* b1f     = (float*)alloc(EDIM * 4);
  float* bias2   = (float*)alloc(CDIM * 4);
  float* sumsq   = (float*)alloc(2 * EDIM * 4);
  float* scale   = (float*)alloc(2 * EDIM * 4);

  hipMemsetAsync(sumsq, 0, 2 * EDIM * 4, stream);
  kprep<<<145, 256, 0, stream>>>(ln_w, ln_b, w1, b1, grn_b, w2, b2, w1p, b1f, bias2);
  kpackB<<<9408, 256, 0, stream>>>(dw_w, Btab);
  kconv<<<3456, 384, 0, stream>>>(x, Btab, dw_b, y);
  kmlp1<<<3456, 512, 0, stream>>>(y, w1p, b1f, h, sumsq);
  kscale<<<2, 384, 0, stream>>>(sumsq, grn_w, scale);
  kpackw2<<<288, 256, 0, stream>>>(scale, w2, w2s);
  kmlp2<<<3456, 256, 0, stream>>>(h, w2s, bias2, x, out);
}